// Round 1
// baseline (93.813 us; speedup 1.0000x reference)
//
#include <hip/hip_runtime.h>

#define NN 512
#define TT 8
#define DD 64

// ---------------------------------------------------------------------------
// Kernel 1: projection.
//   L[t][n][h] = sum_d x[n][t][d] * W1[d][h]
//   R[t][n][h] = sum_d x[n][t][d] * W1[64+d][h] + b1[h]   (b1 folded into R)
// Layout: thread owns one output column (c in 0..127 -> L half / R half) for
// one n and 4 t's. Weight column kept in VGPRs (loads are coalesced 256B per
// wave, W1 is L2-resident). x reads are wave-uniform -> broadcast from L1.
// Pure VALU inner loop: 64 fma per (n,t).
// ---------------------------------------------------------------------------
__global__ __launch_bounds__(256) void k1_proj(const float* __restrict__ x,
                                               const float* __restrict__ W1,
                                               const float* __restrict__ b1,
                                               float* __restrict__ L,
                                               float* __restrict__ R)
{
    int g    = blockIdx.x * 256 + threadIdx.x;   // 0..131071
    int c    = g & 127;
    int h    = c & 63;
    int half = c >> 6;            // 0 -> L, 1 -> R
    int pair = g >> 7;            // 0..1023
    int n    = pair >> 1;         // 0..511
    int t0   = (pair & 1) * 4;    // t-split for 2x wave count

    // Load weight column W1[(half*64 + d)][h], d = 0..63 into registers.
    float wcol[DD];
    const float* wbase = W1 + (half << 6) * DD + h;
#pragma unroll
    for (int d = 0; d < DD; ++d) wcol[d] = wbase[d << 6];

    float bias = half ? b1[h] : 0.0f;
    float* outbase = half ? R : L;

#pragma unroll
    for (int tt = 0; tt < 4; ++tt) {
        int t = t0 + tt;
        const float4* xr = (const float4*)(x + n * (TT * DD) + t * DD);
        float acc = 0.0f;
#pragma unroll
        for (int d4 = 0; d4 < 16; ++d4) {
            float4 xv = xr[d4];
            acc = fmaf(xv.x, wcol[d4 * 4 + 0], acc);
            acc = fmaf(xv.y, wcol[d4 * 4 + 1], acc);
            acc = fmaf(xv.z, wcol[d4 * 4 + 2], acc);
            acc = fmaf(xv.w, wcol[d4 * 4 + 3], acc);
        }
        outbase[t * (NN * DD) + n * DD + h] = acc + bias;
    }
}

// ---------------------------------------------------------------------------
// Kernel 2: pairwise relation.
//   A[i][j] = sum_t wts[t] * relu( sum_d relu(L[t,i,d]+R[t,j,d]) * w2[d] + b2 )
// 256 blocks (1/CU), 256 threads, 32x32 tile, 2x2 outputs/thread.
// L/R per-t tiles double-buffered in LDS; XOR-swizzled float4 columns so the
// 16-distinct-row R read is exactly 2-way banked (free). wts = softmax(a)*decay
// computed redundantly per block by thread 0 (negligible).
// ---------------------------------------------------------------------------
__global__ __launch_bounds__(256) void k2_main(const float* __restrict__ L,
                                               const float* __restrict__ R,
                                               const float* __restrict__ W2,
                                               const float* __restrict__ b2,
                                               const float* __restrict__ a,
                                               float* __restrict__ A)
{
    __shared__ float Ls[2][32 * 64];
    __shared__ float Rs[2][32 * 64];
    __shared__ float w2s[64];
    __shared__ float wts[8];

    const int tid = threadIdx.x;
    const int i0  = blockIdx.y << 5;
    const int j0  = blockIdx.x << 5;
    const int tj  = tid & 15;
    const int ti  = tid >> 4;

    if (tid < 64) w2s[tid] = W2[tid];
    if (tid == 0) {
        float av[8], e[8];
        float m = -1e30f;
        for (int t = 0; t < 8; ++t) { av[t] = a[t]; m = fmaxf(m, av[t]); }
        float s = 0.0f;
        for (int t = 0; t < 8; ++t) { e[t] = expf(av[t] - m); s += e[t]; }
        for (int t = 0; t < 8; ++t)
            wts[t] = (e[t] / s) * (1.0f + 0.5f * expf(-0.1f * (float)(7 - t)));
    }

    const float b2v = b2[0];

    // register staging for double buffer
    float4 lr0, lr1, rr0, rr1;
    auto stage_load = [&](int t) {
        const float4* lp = (const float4*)(L + t * (NN * DD) + i0 * DD);
        const float4* rp = (const float4*)(R + t * (NN * DD) + j0 * DD);
        lr0 = lp[tid]; lr1 = lp[tid + 256];
        rr0 = rp[tid]; rr1 = rp[tid + 256];
    };
    auto put = [&](float* base, int e, float4 v) {
        int row = e >> 4, col4 = e & 15;
        int pos = (row << 6) + ((col4 ^ ((row >> 1) & 7)) << 2);
        *(float4*)(base + pos) = v;
    };
    auto write_lds = [&](int buf) {
        put(Ls[buf], tid, lr0); put(Ls[buf], tid + 256, lr1);
        put(Rs[buf], tid, rr0); put(Rs[buf], tid + 256, rr1);
    };

    float acc00 = 0.f, acc01 = 0.f, acc10 = 0.f, acc11 = 0.f;
    const int riL0 = (2 * ti) << 6, riL1 = (2 * ti + 1) << 6;
    const int riR0 = (2 * tj) << 6, riR1 = (2 * tj + 1) << 6;
    const int swLb = ti & 7, swRb = tj & 7;

    stage_load(0);
    write_lds(0);
    stage_load(1);
    __syncthreads();

    for (int t = 0; t < 8; ++t) {
        const float* LB = Ls[t & 1];
        const float* RB = Rs[t & 1];
        float s00 = 0.f, s01 = 0.f, s10 = 0.f, s11 = 0.f;
#pragma unroll
        for (int d4 = 0; d4 < 16; ++d4) {
            const int swL = (d4 ^ swLb) << 2;
            const int swR = (d4 ^ swRb) << 2;
            float4 l0 = *(const float4*)(LB + riL0 + swL);
            float4 l1 = *(const float4*)(LB + riL1 + swL);
            float4 r0 = *(const float4*)(RB + riR0 + swR);
            float4 r1 = *(const float4*)(RB + riR1 + swR);
            float4 wv = *(const float4*)(w2s + (d4 << 2));
            s00 = fmaf(fmaxf(l0.x + r0.x, 0.f), wv.x, s00);
            s01 = fmaf(fmaxf(l0.x + r1.x, 0.f), wv.x, s01);
            s10 = fmaf(fmaxf(l1.x + r0.x, 0.f), wv.x, s10);
            s11 = fmaf(fmaxf(l1.x + r1.x, 0.f), wv.x, s11);
            s00 = fmaf(fmaxf(l0.y + r0.y, 0.f), wv.y, s00);
            s01 = fmaf(fmaxf(l0.y + r1.y, 0.f), wv.y, s01);
            s10 = fmaf(fmaxf(l1.y + r0.y, 0.f), wv.y, s10);
            s11 = fmaf(fmaxf(l1.y + r1.y, 0.f), wv.y, s11);
            s00 = fmaf(fmaxf(l0.z + r0.z, 0.f), wv.z, s00);
            s01 = fmaf(fmaxf(l0.z + r1.z, 0.f), wv.z, s01);
            s10 = fmaf(fmaxf(l1.z + r0.z, 0.f), wv.z, s10);
            s11 = fmaf(fmaxf(l1.z + r1.z, 0.f), wv.z, s11);
            s00 = fmaf(fmaxf(l0.w + r0.w, 0.f), wv.w, s00);
            s01 = fmaf(fmaxf(l0.w + r1.w, 0.f), wv.w, s01);
            s10 = fmaf(fmaxf(l1.w + r0.w, 0.f), wv.w, s10);
            s11 = fmaf(fmaxf(l1.w + r1.w, 0.f), wv.w, s11);
        }
        const float wt = wts[t];
        acc00 = fmaf(wt, fmaxf(s00 + b2v, 0.f), acc00);
        acc01 = fmaf(wt, fmaxf(s01 + b2v, 0.f), acc01);
        acc10 = fmaf(wt, fmaxf(s10 + b2v, 0.f), acc10);
        acc11 = fmaf(wt, fmaxf(s11 + b2v, 0.f), acc11);
        if (t < 7) {
            write_lds((t + 1) & 1);
            if (t + 2 < 8) stage_load(t + 2);
            __syncthreads();
        }
    }

    const int i = i0 + 2 * ti;
    const int j = j0 + 2 * tj;
    *(float2*)(A + i * NN + j)       = make_float2(acc00, acc01);
    *(float2*)(A + (i + 1) * NN + j) = make_float2(acc10, acc11);
}

extern "C" void kernel_launch(void* const* d_in, const int* in_sizes, int n_in,
                              void* d_out, int out_size, void* d_ws, size_t ws_size,
                              hipStream_t stream) {
    const float* x  = (const float*)d_in[0];
    const float* W1 = (const float*)d_in[1];
    const float* b1 = (const float*)d_in[2];
    const float* W2 = (const float*)d_in[3];
    const float* b2 = (const float*)d_in[4];
    const float* a  = (const float*)d_in[5];
    float* A = (float*)d_out;

    float* L = (float*)d_ws;                 // 8*512*64 f32 = 1 MB
    float* R = L + NN * TT * DD;             // 1 MB

    k1_proj<<<512, 256, 0, stream>>>(x, W1, b1, L, R);
    k2_main<<<dim3(16, 16), 256, 0, stream>>>(L, R, W2, b2, a, A);
}

// Round 3
// 84.544 us; speedup vs baseline: 1.1096x; 1.1096x over previous
//
#include <hip/hip_runtime.h>

#define NN 512
#define TT 8
#define DD 64

// ---------------------------------------------------------------------------
// Kernel 1: projection.
//   L[t][n][h] = sum_d x[n][t][d] * W1[d][h]
//   R[t][n][h] = sum_d x[n][t][d] * W1[64+d][h] + b1[h]   (b1 folded into R)
// 512 blocks x 256 thr = 2 waves/SIMD. Weight column in VGPRs (coalesced
// 256B/wave loads, W1 L2-resident); x reads wave-uniform broadcasts.
// ---------------------------------------------------------------------------
__global__ __launch_bounds__(256) void k1_proj(const float* __restrict__ x,
                                               const float* __restrict__ W1,
                                               const float* __restrict__ b1,
                                               float* __restrict__ L,
                                               float* __restrict__ R)
{
    int g    = blockIdx.x * 256 + threadIdx.x;   // 0..131071
    int c    = g & 127;
    int h    = c & 63;
    int half = c >> 6;            // 0 -> L, 1 -> R
    int pair = g >> 7;            // 0..1023
    int n    = pair >> 1;         // 0..511
    int t0   = (pair & 1) * 4;    // t-split for 2x wave count

    float wcol[DD];
    const float* wbase = W1 + (half << 6) * DD + h;
#pragma unroll
    for (int d = 0; d < DD; ++d) wcol[d] = wbase[d << 6];

    float bias = half ? b1[h] : 0.0f;
    float* outbase = half ? R : L;

#pragma unroll
    for (int tt = 0; tt < 4; ++tt) {
        int t = t0 + tt;
        const float4* xr = (const float4*)(x + n * (TT * DD) + t * DD);
        float acc = 0.0f;
#pragma unroll
        for (int d4 = 0; d4 < 16; ++d4) {
            float4 xv = xr[d4];
            acc = fmaf(xv.x, wcol[d4 * 4 + 0], acc);
            acc = fmaf(xv.y, wcol[d4 * 4 + 1], acc);
            acc = fmaf(xv.z, wcol[d4 * 4 + 2], acc);
            acc = fmaf(xv.w, wcol[d4 * 4 + 3], acc);
        }
        outbase[t * (NN * DD) + n * DD + h] = acc + bias;
    }
}

// ---------------------------------------------------------------------------
// Kernel 2: pairwise relation, t-parallel within block.
//   A[i][j] = sum_t wts[t] * relu( sum_d relu(L[t,i,d]+R[t,j,d]) * w2[d] + b2 )
// 256 blocks (1/CU) x 1024 threads (4 waves/SIMD). All 8 t-tiles staged once
// into 128KB dynamic LDS (XOR-swizzled float4 columns -> R reads 2-way = free).
// 4 t-groups of 256 threads each compute the full 32x32 tile for 2 t's;
// cross-group reduce through LDS (aliased over dead L-tiles).
// ---------------------------------------------------------------------------
__global__ __launch_bounds__(1024, 4) void k2_main(const float* __restrict__ L,
                                                   const float* __restrict__ R,
                                                   const float* __restrict__ W2,
                                                   const float* __restrict__ b2,
                                                   const float* __restrict__ a,
                                                   float* __restrict__ A)
{
    extern __shared__ float S[];
    // layout (floats): Ls tile t at t*2048, Rs tile t at 16384 + t*2048,
    // w2s at 32768 (64 floats). Reduce buffer aliases S[0..3071] after compute.
    float* const w2s = S + 32768;

    const int tid = threadIdx.x;
    const int i0  = blockIdx.y << 5;
    const int j0  = blockIdx.x << 5;

    // ---- stage all 8 t-tiles of L(i-rows) and R(j-rows): 8192 float4 total
#pragma unroll
    for (int k = 0; k < 8; ++k) {
        int e    = tid + (k << 10);   // 0..8191
        int half = e >> 12;           // 0: L, 1: R
        int q    = e & 4095;
        int t    = q >> 9;            // tile index
        int w    = q & 511;           // float4 index within 32x64 tile
        int row  = w >> 4;
        int c4   = w & 15;
        const float* src = half ? (R + t * (NN * DD) + (j0 + row) * DD)
                                : (L + t * (NN * DD) + (i0 + row) * DD);
        float4 v = ((const float4*)src)[c4];
        float* dst = S + (half ? 16384 : 0) + t * 2048 + (row << 6)
                       + ((c4 ^ ((row >> 1) & 7)) << 2);
        *(float4*)dst = v;
    }
    if (tid < 64) w2s[tid] = W2[tid];

    // ---- per-thread softmax weights for this thread's two t's (registers)
    const int g  = tid >> 8;          // t-group 0..3
    const int id = tid & 255;
    float wt0, wt1;
    {
        float av[8];
#pragma unroll
        for (int t = 0; t < 8; ++t) av[t] = a[t];
        float m = av[0];
#pragma unroll
        for (int t = 1; t < 8; ++t) m = fmaxf(m, av[t]);
        float ssum = 0.0f;
#pragma unroll
        for (int t = 0; t < 8; ++t) ssum += expf(av[t] - m);
        float inv = 1.0f / ssum;
        int ta = 2 * g, tb = 2 * g + 1;
        wt0 = expf(av[ta] - m) * inv * (1.0f + 0.5f * expf(-0.1f * (float)(7 - ta)));
        wt1 = expf(av[tb] - m) * inv * (1.0f + 0.5f * expf(-0.1f * (float)(7 - tb)));
    }
    const float b2v = b2[0];

    __syncthreads();

    // ---- compute: each group g does t = 2g, 2g+1 over the full 32x32 tile
    const int tj = id & 15;
    const int ti = id >> 4;
    const int riL0 = (2 * ti) << 6,     riL1 = (2 * ti + 1) << 6;
    const int riR0 = (2 * tj) << 6,     riR1 = (2 * tj + 1) << 6;
    const int swLb = ti & 7,            swRb = tj & 7;

    float acc00 = 0.f, acc01 = 0.f, acc10 = 0.f, acc11 = 0.f;

#pragma unroll
    for (int tt = 0; tt < 2; ++tt) {
        const int t = 2 * g + tt;
        const float* LB = S + t * 2048;
        const float* RB = S + 16384 + t * 2048;
        float s00 = 0.f, s01 = 0.f, s10 = 0.f, s11 = 0.f;
#pragma unroll
        for (int d4 = 0; d4 < 16; ++d4) {
            const int swL = (d4 ^ swLb) << 2;
            const int swR = (d4 ^ swRb) << 2;
            float4 l0 = *(const float4*)(LB + riL0 + swL);
            float4 l1 = *(const float4*)(LB + riL1 + swL);
            float4 r0 = *(const float4*)(RB + riR0 + swR);
            float4 r1 = *(const float4*)(RB + riR1 + swR);
            float4 wv = *(const float4*)(w2s + (d4 << 2));
            s00 = fmaf(fmaxf(l0.x + r0.x, 0.f), wv.x, s00);
            s01 = fmaf(fmaxf(l0.x + r1.x, 0.f), wv.x, s01);
            s10 = fmaf(fmaxf(l1.x + r0.x, 0.f), wv.x, s10);
            s11 = fmaf(fmaxf(l1.x + r1.x, 0.f), wv.x, s11);
            s00 = fmaf(fmaxf(l0.y + r0.y, 0.f), wv.y, s00);
            s01 = fmaf(fmaxf(l0.y + r1.y, 0.f), wv.y, s01);
            s10 = fmaf(fmaxf(l1.y + r0.y, 0.f), wv.y, s10);
            s11 = fmaf(fmaxf(l1.y + r1.y, 0.f), wv.y, s11);
            s00 = fmaf(fmaxf(l0.z + r0.z, 0.f), wv.z, s00);
            s01 = fmaf(fmaxf(l0.z + r1.z, 0.f), wv.z, s01);
            s10 = fmaf(fmaxf(l1.z + r0.z, 0.f), wv.z, s10);
            s11 = fmaf(fmaxf(l1.z + r1.z, 0.f), wv.z, s11);
            s00 = fmaf(fmaxf(l0.w + r0.w, 0.f), wv.w, s00);
            s01 = fmaf(fmaxf(l0.w + r1.w, 0.f), wv.w, s01);
            s10 = fmaf(fmaxf(l1.w + r0.w, 0.f), wv.w, s10);
            s11 = fmaf(fmaxf(l1.w + r1.w, 0.f), wv.w, s11);
        }
        const float wt = tt ? wt1 : wt0;
        acc00 = fmaf(wt, fmaxf(s00 + b2v, 0.f), acc00);
        acc01 = fmaf(wt, fmaxf(s01 + b2v, 0.f), acc01);
        acc10 = fmaf(wt, fmaxf(s10 + b2v, 0.f), acc10);
        acc11 = fmaf(wt, fmaxf(s11 + b2v, 0.f), acc11);
    }

    // ---- cross-group reduce via LDS (aliased over dead L-tiles)
    __syncthreads();                  // compute done everywhere; S[0..] dead
    if (g > 0) {
        ((float4*)S)[(g - 1) * 256 + id] = make_float4(acc00, acc01, acc10, acc11);
    }
    __syncthreads();
    if (g == 0) {
#pragma unroll
        for (int gg = 0; gg < 3; ++gg) {
            float4 p = ((const float4*)S)[gg * 256 + id];
            acc00 += p.x; acc01 += p.y; acc10 += p.z; acc11 += p.w;
        }
        const int i = i0 + 2 * ti;
        const int j = j0 + 2 * tj;
        *(float2*)(A + i * NN + j)       = make_float2(acc00, acc01);
        *(float2*)(A + (i + 1) * NN + j) = make_float2(acc10, acc11);
    }
}

extern "C" void kernel_launch(void* const* d_in, const int* in_sizes, int n_in,
                              void* d_out, int out_size, void* d_ws, size_t ws_size,
                              hipStream_t stream) {
    const float* x  = (const float*)d_in[0];
    const float* W1 = (const float*)d_in[1];
    const float* b1 = (const float*)d_in[2];
    const float* W2 = (const float*)d_in[3];
    const float* b2 = (const float*)d_in[4];
    const float* a  = (const float*)d_in[5];
    float* A = (float*)d_out;

    float* L = (float*)d_ws;                 // 8*512*64 f32 = 1 MB
    float* R = L + NN * TT * DD;             // 1 MB

    k1_proj<<<512, 256, 0, stream>>>(x, W1, b1, L, R);

    size_t ldsBytes = (32768 + 64) * sizeof(float);   // ~128.3 KB
    k2_main<<<dim3(16, 16), 1024, ldsBytes, stream>>>(L, R, W2, b2, a, A);
}

// Round 5
// 84.045 us; speedup vs baseline: 1.1162x; 1.0059x over previous
//
#include <hip/hip_runtime.h>

#define NN 512
#define TT 8
#define DD 64

// ---------------------------------------------------------------------------
// Kernel 1: projection.
//   L[t][n][h] = sum_d x[n][t][d] * W1[d][h]
//   R[t][n][h] = sum_d x[n][t][d] * W1[64+d][h] + b1[h]   (b1 folded into R)
// 512 blocks x 256 thr. Weight column in VGPRs (coalesced 256B/wave loads,
// W1 L2-resident); x reads wave-uniform broadcasts. Pure VALU inner loop.
// ---------------------------------------------------------------------------
__global__ __launch_bounds__(256) void k1_proj(const float* __restrict__ x,
                                               const float* __restrict__ W1,
                                               const float* __restrict__ b1,
                                               float* __restrict__ L,
                                               float* __restrict__ R)
{
    int g    = blockIdx.x * 256 + threadIdx.x;   // 0..131071
    int c    = g & 127;
    int h    = c & 63;
    int half = c >> 6;            // 0 -> L, 1 -> R
    int pair = g >> 7;            // 0..1023
    int n    = pair >> 1;         // 0..511
    int t0   = (pair & 1) * 4;    // t-split for 2x wave count

    float wcol[DD];
    const float* wbase = W1 + (half << 6) * DD + h;
#pragma unroll
    for (int d = 0; d < DD; ++d) wcol[d] = wbase[d << 6];

    float bias = half ? b1[h] : 0.0f;
    float* outbase = half ? R : L;

#pragma unroll
    for (int tt = 0; tt < 4; ++tt) {
        int t = t0 + tt;
        const float4* xr = (const float4*)(x + n * (TT * DD) + t * DD);
        float acc = 0.0f;
#pragma unroll
        for (int d4 = 0; d4 < 16; ++d4) {
            float4 xv = xr[d4];
            acc = fmaf(xv.x, wcol[d4 * 4 + 0], acc);
            acc = fmaf(xv.y, wcol[d4 * 4 + 1], acc);
            acc = fmaf(xv.z, wcol[d4 * 4 + 2], acc);
            acc = fmaf(xv.w, wcol[d4 * 4 + 3], acc);
        }
        outbase[t * (NN * DD) + n * DD + h] = acc + bias;
    }
}

// ---------------------------------------------------------------------------
// Kernel 2: pairwise relation. 256 blocks x 512 threads (8 waves).
//   A[i][j] = sum_t wts[t] * relu( sum_d relu(L[t,i,d]+R[t,j,d]) * w2[d] + b2 )
// Wave w computes the FULL 32x32 tile for t=w: 64 lanes in an 8x8 grid, 4x4
// outputs per lane -> 0.5 ds_read_b128 per output (2x less LDS traffic than
// 2x2 tiling). No barriers during compute. All 8 t-tiles of L/R staged once
// in 128KB LDS, XOR-swizzled so reads are <=2-way banked (free). Partials
// (wt-scaled) reduced through LDS aliased over the dead L-tiles.
// ---------------------------------------------------------------------------
__global__ __launch_bounds__(512) void k2_main(const float* __restrict__ L,
                                               const float* __restrict__ R,
                                               const float* __restrict__ W2,
                                               const float* __restrict__ b2,
                                               const float* __restrict__ a,
                                               float* __restrict__ A)
{
    extern __shared__ float S[];
    // floats: L tile t at t*2048, R tile t at 16384 + t*2048, w2s at 32768.
    // Partial buffer P (8 x 1024 floats) aliases S[0..8191] after compute.
    float* const w2s = S + 32768;

    const int tid = threadIdx.x;
    const int i0  = blockIdx.y << 5;
    const int j0  = blockIdx.x << 5;

    // ---- stage all 8 t-tiles of L(i-rows) and R(j-rows): 8192 float4
#pragma unroll
    for (int k = 0; k < 16; ++k) {
        int e    = tid + (k << 9);    // 0..8191
        int half = e >> 12;           // 0: L, 1: R
        int q    = e & 4095;
        int t    = q >> 9;
        int w    = q & 511;           // float4 index within 32x64 tile
        int row  = w >> 4;
        int c4   = w & 15;
        const float* src = half ? (R + t * (NN * DD) + (j0 + row) * DD)
                                : (L + t * (NN * DD) + (i0 + row) * DD);
        float4 v = ((const float4*)src)[c4];
        float* dst = S + (half ? 16384 : 0) + t * 2048 + (row << 6)
                       + ((c4 ^ ((row >> 1) & 7)) << 2);
        *(float4*)dst = v;
    }
    if (tid < 64) w2s[tid] = W2[tid];

    const int wv   = tid >> 6;        // wave id == t
    const int lane = tid & 63;
    const int tjx  = lane & 7;        // j block (4 cols)
    const int tiy  = lane >> 3;       // i block (4 rows)

    // softmax weight for this wave's t (registers, redundant per thread)
    float wt;
    {
        float av[8];
#pragma unroll
        for (int t = 0; t < 8; ++t) av[t] = a[t];
        float m = av[0];
#pragma unroll
        for (int t = 1; t < 8; ++t) m = fmaxf(m, av[t]);
        float ssum = 0.0f;
#pragma unroll
        for (int t = 0; t < 8; ++t) ssum += expf(av[t] - m);
        wt = expf(av[wv] - m) / ssum
           * (1.0f + 0.5f * expf(-0.1f * (float)(7 - wv)));
    }
    const float b2v = b2[0];

    __syncthreads();

    // ---- compute: wave wv does t=wv over the whole 32x32 tile, 4x4/lane
    const float* LB = S + wv * 2048;
    const float* RB = S + 16384 + wv * 2048;

    // per-row base offsets and swizzle keys (rows fixed for the whole loop)
    int lbase[4], rbase[4], lsw[4], rsw[4];
#pragma unroll
    for (int r = 0; r < 4; ++r) {
        int li = 4 * tiy + r;
        int rj = 4 * tjx + r;
        lbase[r] = li << 6;  lsw[r] = (li >> 1) & 7;
        rbase[r] = rj << 6;  rsw[r] = (rj >> 1) & 7;
    }

    float acc[4][4];
#pragma unroll
    for (int p = 0; p < 4; ++p)
#pragma unroll
        for (int q = 0; q < 4; ++q) acc[p][q] = 0.0f;

#pragma unroll 4
    for (int d4 = 0; d4 < 16; ++d4) {
        float4 lv[4], rv[4];
#pragma unroll
        for (int r = 0; r < 4; ++r)
            lv[r] = *(const float4*)(LB + lbase[r] + ((d4 ^ lsw[r]) << 2));
#pragma unroll
        for (int r = 0; r < 4; ++r)
            rv[r] = *(const float4*)(RB + rbase[r] + ((d4 ^ rsw[r]) << 2));
        float4 w4 = *(const float4*)(w2s + (d4 << 2));
#pragma unroll
        for (int p = 0; p < 4; ++p) {
#pragma unroll
            for (int q = 0; q < 4; ++q) {
                float s = acc[p][q];
                s = fmaf(fmaxf(lv[p].x + rv[q].x, 0.f), w4.x, s);
                s = fmaf(fmaxf(lv[p].y + rv[q].y, 0.f), w4.y, s);
                s = fmaf(fmaxf(lv[p].z + rv[q].z, 0.f), w4.z, s);
                s = fmaf(fmaxf(lv[p].w + rv[q].w, 0.f), w4.w, s);
                acc[p][q] = s;
            }
        }
    }

    // ---- epilogue per wave: relu + weight, dump partial into LDS
    __syncthreads();                  // all tile reads done; S[0..8191] dead
    float* const P = S;               // 8 x 1024 floats
#pragma unroll
    for (int p = 0; p < 4; ++p) {
        float4 v = make_float4(
            wt * fmaxf(acc[p][0] + b2v, 0.f),
            wt * fmaxf(acc[p][1] + b2v, 0.f),
            wt * fmaxf(acc[p][2] + b2v, 0.f),
            wt * fmaxf(acc[p][3] + b2v, 0.f));
        *(float4*)(P + (wv << 10) + ((4 * tiy + p) << 5) + (tjx << 2)) = v;
    }
    __syncthreads();

    // ---- cross-t reduce + store: 512 threads, 2 outputs each
#pragma unroll
    for (int e = tid; e < 1024; e += 512) {
        float s = 0.0f;
#pragma unroll
        for (int t = 0; t < 8; ++t) s += P[(t << 10) + e];
        A[(i0 + (e >> 5)) * NN + j0 + (e & 31)] = s;
    }
}

extern "C" void kernel_launch(void* const* d_in, const int* in_sizes, int n_in,
                              void* d_out, int out_size, void* d_ws, size_t ws_size,
                              hipStream_t stream) {
    const float* x  = (const float*)d_in[0];
    const float* W1 = (const float*)d_in[1];
    const float* b1 = (const float*)d_in[2];
    const float* W2 = (const float*)d_in[3];
    const float* b2 = (const float*)d_in[4];
    const float* a  = (const float*)d_in[5];
    float* A = (float*)d_out;

    float* L = (float*)d_ws;                 // 8*512*64 f32 = 1 MB
    float* R = L + NN * TT * DD;             // 1 MB

    k1_proj<<<512, 256, 0, stream>>>(x, W1, b1, L, R);

    size_t ldsBytes = (32768 + 64) * sizeof(float);   // ~128.3 KB
    k2_main<<<dim3(16, 16), 512, ldsBytes, stream>>>(L, R, W2, b2, a, A);
}